// Round 9
// baseline (956.766 us; speedup 1.0000x reference)
//
#include <hip/hip_runtime.h>
#include <math.h>

#define TPB 256
static constexpr int BTT = 192;    // B*T
static constexpr int NN  = 512;    // nodes
static constexpr int DD  = 128;    // feature dim
static constexpr float SCALE = 0.25f; // 1/sqrt(16)
static constexpr float LNEPS = 1e-5f;

typedef _Float16 half8 __attribute__((ext_vector_type(8)));
typedef short bf16x8 __attribute__((ext_vector_type(8)));
typedef float floatx4 __attribute__((ext_vector_type(4)));
typedef unsigned short ushort4v __attribute__((ext_vector_type(4)));

// ---------------- exact 3-limb bf16 split (truncation; q == h+m+l exactly) ----------------
__device__ __forceinline__ void split3(float q, unsigned short& h, unsigned short& m,
                                       unsigned short& l) {
  unsigned uh = __float_as_uint(q) & 0xFFFF0000u;
  float fh = __uint_as_float(uh);
  float r1 = q - fh;                       // exact
  unsigned um = __float_as_uint(r1) & 0xFFFF0000u;
  float fm = __uint_as_float(um);
  float r2 = r1 - fm;                      // exact, fits in bf16
  unsigned ul = __float_as_uint(r2) & 0xFFFF0000u;
  h = (unsigned short)(uh >> 16);
  m = (unsigned short)(um >> 16);
  l = (unsigned short)(ul >> 16);
}

// ---------------- add + limb-plane emit: xr = x+adj (fp32) and xrL [n][3][128] bf16 ----------------
__global__ void k_add(const float* __restrict__ x, const float* __restrict__ g,
                      float* __restrict__ y, unsigned short* __restrict__ yl, int n4) {
  int i = blockIdx.x * blockDim.x + threadIdx.x;
  if (i >= n4) return;
  float4 a = ((const float4*)x)[i], b = ((const float4*)g)[i];
  float4 s = make_float4(a.x + b.x, a.y + b.y, a.z + b.z, a.w + b.w);
  ((float4*)y)[i] = s;
  unsigned short h0, m0, l0, h1, m1, l1, h2, m2, l2, h3, m3, l3;
  split3(s.x, h0, m0, l0); split3(s.y, h1, m1, l1);
  split3(s.z, h2, m2, l2); split3(s.w, h3, m3, l3);
  ushort4v h = {h0, h1, h2, h3};
  ushort4v m = {m0, m1, m2, m3};
  ushort4v l = {l0, l1, l2, l3};
  int n = i >> 5, d0 = (i & 31) << 2;
  unsigned short* base = yl + (long)n * 384 + d0;
  *(ushort4v*)(base)       = h;
  *(ushort4v*)(base + 128) = m;
  *(ushort4v*)(base + 256) = l;
}

// ---------------- one-shot: W^T limb planes for Wq, Wk: WT[mat][limb][col][k] ----------------
__global__ void k_prep_w(const float* __restrict__ Wq, const float* __restrict__ Wk,
                         unsigned short* __restrict__ WT) {
  const float* W = blockIdx.x ? Wk : Wq;
  unsigned short* dst = WT + (long)blockIdx.x * 3 * 16384;
  for (int u = threadIdx.x; u < 4096; u += TPB) {
    int k = u >> 5, c4 = (u & 31) << 2;
    float4 v = *(const float4*)(W + (long)k * DD + c4);
    unsigned short h[4], m[4], l[4];
    split3(v.x, h[0], m[0], l[0]); split3(v.y, h[1], m[1], l[1]);
    split3(v.z, h[2], m[2], l[2]); split3(v.w, h[3], m[3], l[3]);
    #pragma unroll
    for (int i = 0; i < 4; ++i) {
      dst[          (long)(c4 + i) * DD + k] = h[i];
      dst[16384   + (long)(c4 + i) * DD + k] = m[i];
      dst[2*16384 + (long)(c4 + i) * DD + k] = l[i];
    }
  }
}

// ---- Q/K projection via limb MFMA: C(planes [row][3][128]) = xr @ W + b ----
__global__ __launch_bounds__(TPB, 2)
void k_gemm_qk_limb(const unsigned short* __restrict__ xrL,
                    const unsigned short* __restrict__ WT,
                    const float* __restrict__ bias, unsigned short* __restrict__ C) {
  __shared__ unsigned short L[6][128][40];
  const int tid = threadIdx.x;
  const int lane = tid & 63;
  const int wave = tid >> 6;
  const int frow = lane & 15;
  const int kgrp = lane >> 4;
  const int rbase = wave * 32;
  const long rowblk = (long)blockIdx.x * 128;

  floatx4 acc[2][8];
  #pragma unroll
  for (int i = 0; i < 2; ++i)
    #pragma unroll
    for (int j = 0; j < 8; ++j)
      acc[i][j] = (floatx4){0.f, 0.f, 0.f, 0.f};

  for (int k0 = 0; k0 < 128; k0 += 32) {
    __syncthreads();
    for (int u = tid; u < 6144; u += TPB) {
      int pl = u >> 10, rem = u & 1023;
      int row = rem >> 3, k4 = (rem & 7) << 2;
      const unsigned short* src = (pl < 3)
          ? xrL + (rowblk + row) * 384 + pl * 128 + k0 + k4
          : WT + (long)(pl - 3) * 16384 + (long)row * DD + k0 + k4;
      *(ushort4v*)&L[pl][row][k4] = *(const ushort4v*)src;
    }
    __syncthreads();
    const int mk = kgrp * 8;
    bf16x8 aH0 = *(const bf16x8*)&L[0][rbase + frow][mk];
    bf16x8 aH1 = *(const bf16x8*)&L[0][rbase + 16 + frow][mk];
    bf16x8 aM0 = *(const bf16x8*)&L[1][rbase + frow][mk];
    bf16x8 aM1 = *(const bf16x8*)&L[1][rbase + 16 + frow][mk];
    bf16x8 aL0 = *(const bf16x8*)&L[2][rbase + frow][mk];
    bf16x8 aL1 = *(const bf16x8*)&L[2][rbase + 16 + frow][mk];
    #pragma unroll
    for (int j = 0; j < 8; ++j) {
      bf16x8 bH = *(const bf16x8*)&L[3][j * 16 + frow][mk];
      bf16x8 bM = *(const bf16x8*)&L[4][j * 16 + frow][mk];
      bf16x8 bL = *(const bf16x8*)&L[5][j * 16 + frow][mk];
      acc[0][j] = __builtin_amdgcn_mfma_f32_16x16x32_bf16(aM0, bM, acc[0][j], 0, 0, 0);
      acc[1][j] = __builtin_amdgcn_mfma_f32_16x16x32_bf16(aM1, bM, acc[1][j], 0, 0, 0);
      acc[0][j] = __builtin_amdgcn_mfma_f32_16x16x32_bf16(aH0, bL, acc[0][j], 0, 0, 0);
      acc[1][j] = __builtin_amdgcn_mfma_f32_16x16x32_bf16(aH1, bL, acc[1][j], 0, 0, 0);
      acc[0][j] = __builtin_amdgcn_mfma_f32_16x16x32_bf16(aL0, bH, acc[0][j], 0, 0, 0);
      acc[1][j] = __builtin_amdgcn_mfma_f32_16x16x32_bf16(aL1, bH, acc[1][j], 0, 0, 0);
      acc[0][j] = __builtin_amdgcn_mfma_f32_16x16x32_bf16(aH0, bM, acc[0][j], 0, 0, 0);
      acc[1][j] = __builtin_amdgcn_mfma_f32_16x16x32_bf16(aH1, bM, acc[1][j], 0, 0, 0);
      acc[0][j] = __builtin_amdgcn_mfma_f32_16x16x32_bf16(aM0, bH, acc[0][j], 0, 0, 0);
      acc[1][j] = __builtin_amdgcn_mfma_f32_16x16x32_bf16(aM1, bH, acc[1][j], 0, 0, 0);
      acc[0][j] = __builtin_amdgcn_mfma_f32_16x16x32_bf16(aH0, bH, acc[0][j], 0, 0, 0);
      acc[1][j] = __builtin_amdgcn_mfma_f32_16x16x32_bf16(aH1, bH, acc[1][j], 0, 0, 0);
    }
  }
  // epilogue: add bias, split exactly into limb planes [row][3][128]
  #pragma unroll
  for (int i = 0; i < 2; ++i)
    #pragma unroll
    for (int j = 0; j < 8; ++j) {
      const int col = j * 16 + frow;
      const float bb = bias[col];
      #pragma unroll
      for (int r = 0; r < 4; ++r) {
        float q = acc[i][j][r] + bb;
        unsigned short h, m, l;
        split3(q, h, m, l);
        long base = (rowblk + rbase + i * 16 + kgrp * 4 + r) * 384 + col;
        C[base] = h; C[base + 128] = m; C[base + 256] = l;
      }
    }
}

// ---------------- GEMM + bias via fp16 MFMA (V: smooth path) ----------------
__global__ __launch_bounds__(TPB, 2)
void k_gemm_bias_f16(const float* __restrict__ A, const float* __restrict__ W,
                     const float* __restrict__ bias, float* __restrict__ C) {
  __shared__ _Float16 At[128][136];
  __shared__ _Float16 Bt[128][136];
  const int tid = threadIdx.x;
  const int lane = tid & 63;
  const int wave = tid >> 6;
  const int frow = lane & 15;
  const int kgrp = lane >> 4;
  const int rbase = wave * 32;
  const long rowblk = (long)blockIdx.x * 128;

  for (int u = tid; u < 128 * 32; u += TPB) {
    int r = u >> 5, k4 = (u & 31) << 2;
    float4 v4 = *(const float4*)(A + (rowblk + r) * DD + k4);
    At[r][k4 + 0] = (_Float16)v4.x; At[r][k4 + 1] = (_Float16)v4.y;
    At[r][k4 + 2] = (_Float16)v4.z; At[r][k4 + 3] = (_Float16)v4.w;
  }
  for (int u = tid; u < 128 * 32; u += TPB) {
    int k = u >> 5, c4 = (u & 31) << 2;
    float4 v4 = *(const float4*)(W + (long)k * DD + c4);
    Bt[c4 + 0][k] = (_Float16)v4.x; Bt[c4 + 1][k] = (_Float16)v4.y;
    Bt[c4 + 2][k] = (_Float16)v4.z; Bt[c4 + 3][k] = (_Float16)v4.w;
  }
  __syncthreads();

  floatx4 acc[2][8];
  #pragma unroll
  for (int i = 0; i < 2; ++i)
    #pragma unroll
    for (int j = 0; j < 8; ++j)
      acc[i][j] = (floatx4){0.f, 0.f, 0.f, 0.f};
  #pragma unroll
  for (int ks = 0; ks < 4; ++ks) {
    const int mk = ks * 32 + kgrp * 8;
    half8 a0 = *(const half8*)&At[rbase + frow][mk];
    half8 a1 = *(const half8*)&At[rbase + 16 + frow][mk];
    #pragma unroll
    for (int j = 0; j < 8; ++j) {
      half8 b = *(const half8*)&Bt[j * 16 + frow][mk];
      acc[0][j] = __builtin_amdgcn_mfma_f32_16x16x32_f16(a0, b, acc[0][j], 0, 0, 0);
      acc[1][j] = __builtin_amdgcn_mfma_f32_16x16x32_f16(a1, b, acc[1][j], 0, 0, 0);
    }
  }
  #pragma unroll
  for (int i = 0; i < 2; ++i)
    #pragma unroll
    for (int j = 0; j < 8; ++j) {
      const int col = j * 16 + frow;
      const float bb = bias[col];
      #pragma unroll
      for (int r = 0; r < 4; ++r)
        C[(rowblk + rbase + i * 16 + kgrp * 4 + r) * DD + col] = acc[i][j][r] + bb;
    }
}

// ---- scores via bf16x3 MFMA (plane-copy staging) + row-softmax partials ----
__global__ __launch_bounds__(TPB, 2)
void k_scores_mfma(const unsigned short* __restrict__ Q, const unsigned short* __restrict__ K,
                   float* __restrict__ S, float* __restrict__ pm,
                   float* __restrict__ ps) {
  int blk = blockIdx.x;            // btc*16 + rt*4 + ct
  int btc = blk >> 4, rt = (blk >> 2) & 3, ct = blk & 3;
  const unsigned short* Qb = Q + ((long)btc * NN + rt * 128) * 384;
  const unsigned short* Kb = K + ((long)btc * NN + ct * 128) * 384;
  float* Sb = S + (long)btc * NN * NN + (long)rt * 128 * NN + ct * 128;

  __shared__ unsigned short L[6][128][40];

  const int tid = threadIdx.x;
  const int lane = tid & 63;
  const int wave = tid >> 6;
  const int frow = lane & 15;
  const int kgrp = lane >> 4;
  const int rbase = wave * 32;

  floatx4 acc[2][8];
  #pragma unroll
  for (int i = 0; i < 2; ++i)
    #pragma unroll
    for (int j = 0; j < 8; ++j)
      acc[i][j] = (floatx4){0.f, 0.f, 0.f, 0.f};

  for (int k0 = 0; k0 < 128; k0 += 32) {
    __syncthreads();
    for (int u = tid; u < 6144; u += TPB) {
      int pl = u >> 10, rem = u & 1023;
      int row = rem >> 3, k4 = (rem & 7) << 2;
      const unsigned short* src = (pl < 3)
          ? Qb + (long)row * 384 + pl * 128 + k0 + k4
          : Kb + (long)row * 384 + (pl - 3) * 128 + k0 + k4;
      *(ushort4v*)&L[pl][row][k4] = *(const ushort4v*)src;
    }
    __syncthreads();

    const int mk = kgrp * 8;
    bf16x8 aH0 = *(const bf16x8*)&L[0][rbase + frow][mk];
    bf16x8 aH1 = *(const bf16x8*)&L[0][rbase + 16 + frow][mk];
    bf16x8 aM0 = *(const bf16x8*)&L[1][rbase + frow][mk];
    bf16x8 aM1 = *(const bf16x8*)&L[1][rbase + 16 + frow][mk];
    bf16x8 aL0 = *(const bf16x8*)&L[2][rbase + frow][mk];
    bf16x8 aL1 = *(const bf16x8*)&L[2][rbase + 16 + frow][mk];
    #pragma unroll
    for (int j = 0; j < 8; ++j) {
      bf16x8 bH = *(const bf16x8*)&L[3][j * 16 + frow][mk];
      bf16x8 bM = *(const bf16x8*)&L[4][j * 16 + frow][mk];
      bf16x8 bL = *(const bf16x8*)&L[5][j * 16 + frow][mk];
      acc[0][j] = __builtin_amdgcn_mfma_f32_16x16x32_bf16(aM0, bM, acc[0][j], 0, 0, 0);
      acc[1][j] = __builtin_amdgcn_mfma_f32_16x16x32_bf16(aM1, bM, acc[1][j], 0, 0, 0);
      acc[0][j] = __builtin_amdgcn_mfma_f32_16x16x32_bf16(aH0, bL, acc[0][j], 0, 0, 0);
      acc[1][j] = __builtin_amdgcn_mfma_f32_16x16x32_bf16(aH1, bL, acc[1][j], 0, 0, 0);
      acc[0][j] = __builtin_amdgcn_mfma_f32_16x16x32_bf16(aL0, bH, acc[0][j], 0, 0, 0);
      acc[1][j] = __builtin_amdgcn_mfma_f32_16x16x32_bf16(aL1, bH, acc[1][j], 0, 0, 0);
      acc[0][j] = __builtin_amdgcn_mfma_f32_16x16x32_bf16(aH0, bM, acc[0][j], 0, 0, 0);
      acc[1][j] = __builtin_amdgcn_mfma_f32_16x16x32_bf16(aH1, bM, acc[1][j], 0, 0, 0);
      acc[0][j] = __builtin_amdgcn_mfma_f32_16x16x32_bf16(aM0, bH, acc[0][j], 0, 0, 0);
      acc[1][j] = __builtin_amdgcn_mfma_f32_16x16x32_bf16(aM1, bH, acc[1][j], 0, 0, 0);
      acc[0][j] = __builtin_amdgcn_mfma_f32_16x16x32_bf16(aH0, bH, acc[0][j], 0, 0, 0);
      acc[1][j] = __builtin_amdgcn_mfma_f32_16x16x32_bf16(aH1, bH, acc[1][j], 0, 0, 0);
    }
  }
  // store S
  #pragma unroll
  for (int i = 0; i < 2; ++i)
    #pragma unroll
    for (int j = 0; j < 8; ++j)
      #pragma unroll
      for (int r = 0; r < 4; ++r)
        Sb[(long)(rbase + i * 16 + kgrp * 4 + r) * NN + j * 16 + frow] =
            acc[i][j][r] * SCALE;
  // per-row partial (max, sumexp) over this 128-col tile
  #pragma unroll
  for (int i = 0; i < 2; ++i)
    #pragma unroll
    for (int r = 0; r < 4; ++r) {
      float mx = -3.4e38f;
      #pragma unroll
      for (int j = 0; j < 8; ++j) mx = fmaxf(mx, acc[i][j][r] * SCALE);
      #pragma unroll
      for (int d = 1; d < 16; d <<= 1) mx = fmaxf(mx, __shfl_xor(mx, d));
      float se = 0.f;
      #pragma unroll
      for (int j = 0; j < 8; ++j) se += __expf(acc[i][j][r] * SCALE - mx);
      #pragma unroll
      for (int d = 1; d < 16; d <<= 1) se += __shfl_xor(se, d);
      if (frow == 0) {
        int row = rbase + i * 16 + kgrp * 4 + r;
        long pidx = ((long)btc * 4 + ct) * NN + rt * 128 + row;
        pm[pidx] = mx; ps[pidx] = se;
      }
    }
}

// ---------------- combine 4 per-tile partials -> lse ----------------
__global__ void k_lse_combine(const float* __restrict__ pm, const float* __restrict__ ps,
                              float* __restrict__ lse, int total) {
  int idx = blockIdx.x * TPB + threadIdx.x;   // btc*512 + n
  if (idx >= total) return;
  int btc = idx >> 9, n = idx & 511;
  float mv[4], sv[4];
  float M = -3.4e38f;
  #pragma unroll
  for (int ct = 0; ct < 4; ++ct) {
    long p = ((long)btc * 4 + ct) * NN + n;
    mv[ct] = pm[p]; sv[ct] = ps[p];
    M = fmaxf(M, mv[ct]);
  }
  float tot = 0.f;
  #pragma unroll
  for (int ct = 0; ct < 4; ++ct) tot += sv[ct] * expf(mv[ct] - M);
  lse[idx] = M + logf(tot);
}

// ---- PV via fp16 MFMA + fused column argmax ----
__global__ __launch_bounds__(TPB, 3)
void k_pv_f16(const float* __restrict__ S, const float* __restrict__ lse,
              const float* __restrict__ V, float* __restrict__ att,
              unsigned long long* __restrict__ cpk) {
  int btc = blockIdx.x >> 3, nt = blockIdx.x & 7;
  const int n0 = nt * 64;
  const float* Sb = S + (long)btc * NN * NN + (long)n0 * NN;
  const float* lb = lse + btc * NN + n0;
  const float* Vb = V + (long)btc * NN * DD;
  float* attb = att + ((long)btc * NN + n0) * DD;
  unsigned long long* cpb = cpk + (long)btc * NN;

  __shared__ _Float16 Ph[64][72];
  __shared__ _Float16 Vt[128][72];
  __shared__ float P32[64][65];
  __shared__ unsigned long long colmax[64];

  const int tid = threadIdx.x;
  const int lane = tid & 63;
  const int wave = tid >> 6;
  const int frow = lane & 15;
  const int kgrp = lane >> 4;
  const int wr = wave * 16;
  const int c = tid & 63, g = tid >> 6;

  floatx4 acc[8];
  #pragma unroll
  for (int j = 0; j < 8; ++j) acc[j] = (floatx4){0.f, 0.f, 0.f, 0.f};

  for (int m0 = 0; m0 < NN; m0 += 64) {
    __syncthreads();
    if (tid < 64) {
      if (m0 > 0) atomicMax(&cpb[m0 - 64 + tid], colmax[tid]);
      colmax[tid] = 0ull;
    }
    for (int u = tid; u < 64 * 16; u += TPB) {
      int n = u >> 4, m4 = (u & 15) << 2;
      float l = lb[n];
      float4 s4 = *(const float4*)(Sb + (long)n * NN + m0 + m4);
      float v0 = s4.x - l, v1 = s4.y - l, v2 = s4.z - l, v3 = s4.w - l;
      P32[n][m4 + 0] = v0; P32[n][m4 + 1] = v1;
      P32[n][m4 + 2] = v2; P32[n][m4 + 3] = v3;
      Ph[n][m4 + 0] = (_Float16)__expf(v0);
      Ph[n][m4 + 1] = (_Float16)__expf(v1);
      Ph[n][m4 + 2] = (_Float16)__expf(v2);
      Ph[n][m4 + 3] = (_Float16)__expf(v3);
    }
    for (int u = tid; u < 2048; u += TPB) {
      int d4 = (u & 31) << 2, m = u >> 5;
      int mc = m ^ (((d4 >> 2) & 7) << 3);
      float4 v4 = *(const float4*)(Vb + (long)(m0 + m) * DD + d4);
      Vt[d4 + 0][mc] = (_Float16)v4.x;
      Vt[d4 + 1][mc] = (_Float16)v4.y;
      Vt[d4 + 2][mc] = (_Float16)v4.z;
      Vt[d4 + 3][mc] = (_Float16)v4.w;
    }
    __syncthreads();
    {
      float best = -3.4e38f;
      int bi = g * 16;
      #pragma unroll
      for (int t = 0; t < 16; ++t) {
        float v = P32[g * 16 + t][c];
        if (v > best) { best = v; bi = g * 16 + t; }
      }
      unsigned key = ~__float_as_uint(best);
      unsigned long long pk =
          ((unsigned long long)key << 32) | (unsigned)(NN - 1 - (n0 + bi));
      atomicMax(&colmax[c], pk);
    }
    #pragma unroll
    for (int ks = 0; ks < 2; ++ks) {
      const int mk = ks * 32 + kgrp * 8;
      half8 a = *(const half8*)&Ph[wr + frow][mk];
      #pragma unroll
      for (int j = 0; j < 8; ++j) {
        const int d = j * 16 + frow;
        const int swz = ((d >> 2) & 7) << 3;
        half8 b = *(const half8*)&Vt[d][mk ^ swz];
        acc[j] = __builtin_amdgcn_mfma_f32_16x16x32_f16(a, b, acc[j], 0, 0, 0);
      }
    }
  }
  __syncthreads();
  if (tid < 64) atomicMax(&cpb[NN - 64 + tid], colmax[tid]);
  #pragma unroll
  for (int j = 0; j < 8; ++j)
    #pragma unroll
    for (int r = 0; r < 4; ++r)
      attb[(long)(wr + kgrp * 4 + r) * DD + j * 16 + frow] = acc[j][r];
}

// ---- gather + Wo + residual + LN + FFN, fp16 MFMA ----
__global__ __launch_bounds__(TPB, 2)
void k_wo_ln_ffn(const float* __restrict__ att, const unsigned long long* __restrict__ cpk,
                 const float* __restrict__ Wo, const float* __restrict__ bo,
                 const float* __restrict__ xr,
                 const float* __restrict__ W1, const float* __restrict__ b1,
                 const float* __restrict__ W2, const float* __restrict__ b2,
                 float* __restrict__ out) {
  const int blk = blockIdx.x, btc = blk >> 2, rt = blk & 3;
  const int n0 = rt * 128;
  const long g0 = (long)btc * NN + n0;
  const float* attb = att + (long)btc * NN * DD;
  const unsigned long long* cpb = cpk + g0;

  __shared__ _Float16 At[128][136];
  __shared__ _Float16 Bt[128][136];

  const int tid = threadIdx.x;
  const int lane = tid & 63;
  const int wave = tid >> 6;
  const int frow = lane & 15;
  const int kgrp = lane >> 4;
  const int rbase = wave * 32;

  auto stage_wT = [&](const float* __restrict__ W) {
    for (int u = tid; u < 128 * 32; u += TPB) {
      int k = u >> 5, c4 = (u & 31) << 2;
      float4 v4 = *(const float4*)(W + (long)k * DD + c4);
      Bt[c4 + 0][k] = (_Float16)v4.x; Bt[c4 + 1][k] = (_Float16)v4.y;
      Bt[c4 + 2][k] = (_Float16)v4.z; Bt[c4 + 3][k] = (_Float16)v4.w;
    }
  };

  floatx4 acc[2][8];
  auto zero_acc = [&]() {
    #pragma unroll
    for (int i = 0; i < 2; ++i)
      #pragma unroll
      for (int j = 0; j < 8; ++j)
        acc[i][j] = (floatx4){0.f, 0.f, 0.f, 0.f};
  };
  auto mfma_tile = [&]() {
    #pragma unroll
    for (int ks = 0; ks < 4; ++ks) {
      const int mk = ks * 32 + kgrp * 8;
      half8 a0 = *(const half8*)&At[rbase + frow][mk];
      half8 a1 = *(const half8*)&At[rbase + 16 + frow][mk];
      #pragma unroll
      for (int j = 0; j < 8; ++j) {
        half8 b = *(const half8*)&Bt[j * 16 + frow][mk];
        acc[0][j] = __builtin_amdgcn_mfma_f32_16x16x32_f16(a0, b, acc[0][j], 0, 0, 0);
        acc[1][j] = __builtin_amdgcn_mfma_f32_16x16x32_f16(a1, b, acc[1][j], 0, 0, 0);
      }
    }
  };

  // Phase A: gathered attended @ Wo
  for (int u = tid; u < 128 * 32; u += TPB) {
    int r = u >> 5, k4 = (u & 31) << 2;
    int src = NN - 1 - (int)(unsigned)(cpb[r] & 0xFFFFFFFFull);
    float4 v4 = *(const float4*)(attb + (long)src * DD + k4);
    At[r][k4 + 0] = (_Float16)v4.x; At[r][k4 + 1] = (_Float16)v4.y;
    At[r][k4 + 2] = (_Float16)v4.z; At[r][k4 + 3] = (_Float16)v4.w;
  }
  stage_wT(Wo);
  __syncthreads();
  zero_acc();
  mfma_tile();
  __syncthreads();

  // bias + residual + LayerNorm in registers
  float v[2][8][4];
  #pragma unroll
  for (int i = 0; i < 2; ++i)
    #pragma unroll
    for (int j = 0; j < 8; ++j) {
      const int col = j * 16 + frow;
      const float bb = bo[col];
      #pragma unroll
      for (int r = 0; r < 4; ++r) {
        const long grow = g0 + rbase + i * 16 + kgrp * 4 + r;
        v[i][j][r] = acc[i][j][r] + bb + xr[grow * DD + col];
      }
    }
  #pragma unroll
  for (int i = 0; i < 2; ++i)
    #pragma unroll
    for (int r = 0; r < 4; ++r) {
      float s = 0.f, ss = 0.f;
      #pragma unroll
      for (int j = 0; j < 8; ++j) { float t = v[i][j][r]; s += t; ss += t * t; }
      #pragma unroll
      for (int d = 1; d < 16; d <<= 1) { s += __shfl_xor(s, d); ss += __shfl_xor(ss, d); }
      float mu = s * (1.f / 128.f);
      float var = ss * (1.f / 128.f) - mu * mu;
      float rs = rsqrtf(var + LNEPS);
      #pragma unroll
      for (int j = 0; j < 8; ++j) v[i][j][r] = (v[i][j][r] - mu) * rs;
    }
  #pragma unroll
  for (int i = 0; i < 2; ++i)
    #pragma unroll
    for (int j = 0; j < 8; ++j)
      #pragma unroll
      for (int r = 0; r < 4; ++r)
        At[rbase + i * 16 + kgrp * 4 + r][j * 16 + frow] = (_Float16)v[i][j][r];
  stage_wT(W1);
  __syncthreads();

  // Phase B: H = relu(LN @ W1 + b1)
  zero_acc();
  mfma_tile();
  __syncthreads();
  #pragma unroll
  for (int i = 0; i < 2; ++i)
    #pragma unroll
    for (int j = 0; j < 8; ++j) {
      const int col = j * 16 + frow;
      const float bb = b1[col];
      #pragma unroll
      for (int r = 0; r < 4; ++r)
        At[rbase + i * 16 + kgrp * 4 + r][col] = (_Float16)fmaxf(acc[i][j][r] + bb, 0.f);
    }
  stage_wT(W2);
  __syncthreads();

  // Phase C: out = H @ W2 + b2
  zero_acc();
  mfma_tile();
  #pragma unroll
  for (int i = 0; i < 2; ++i)
    #pragma unroll
    for (int j = 0; j < 8; ++j) {
      const int col = j * 16 + frow;
      const float bb = b2[col];
      #pragma unroll
      for (int r = 0; r < 4; ++r) {
        const long grow = g0 + rbase + i * 16 + kgrp * 4 + r;
        out[grow * DD + col] = acc[i][j][r] + bb;
      }
    }
}

// ---------------- launch ----------------
extern "C" void kernel_launch(void* const* d_in, const int* in_sizes, int n_in,
                              void* d_out, int out_size, void* d_ws, size_t ws_size,
                              hipStream_t stream) {
  const float* x    = (const float*)d_in[0];
  const float* adj  = (const float*)d_in[1];
  const float* Wq   = (const float*)d_in[2];
  const float* bq   = (const float*)d_in[3];
  const float* Wk   = (const float*)d_in[4];
  const float* bk   = (const float*)d_in[5];
  const float* Wv   = (const float*)d_in[6];
  const float* bv   = (const float*)d_in[7];
  const float* Wo   = (const float*)d_in[8];
  const float* bo   = (const float*)d_in[9];
  const float* W1   = (const float*)d_in[10];
  const float* b1   = (const float*)d_in[11];
  const float* W2   = (const float*)d_in[12];
  const float* b2   = (const float*)d_in[13];
  float* out = (float*)d_out;
  (void)in_sizes; (void)n_in; (void)out_size;

  // constant: WT limb planes for Wq,Wk = 2*3*16384 u16
  const size_t WT_BYTES = 2 * 3 * 16384 * 2;
  // per-bt: xr + xrL + Qpl + Kpl + V + att + S + lse + pm/ps + cpk
  const size_t BT_ROWBYTES = (size_t)NN * DD * 4;                 // 262144
  const size_t PL_BYTES = (size_t)NN * 384 * 2;                   // 393216
  const size_t per_bt = 3 * BT_ROWBYTES + 3 * PL_BYTES + (size_t)NN * NN * 4
                      + (size_t)NN * 4 + 2 * 4 * (size_t)NN * 4 + (size_t)NN * 8;
  static const int divs[] = {192, 96, 64, 48, 32, 24, 16, 12, 8, 6, 4, 3, 2, 1};
  int CH = 1;
  for (int i = 0; i < 14; ++i) {
    if ((size_t)divs[i] * per_bt + WT_BYTES + 16384 <= ws_size) { CH = divs[i]; break; }
  }

  char* ws = (char*)d_ws;
  size_t off = 0;
  auto alloc = [&](size_t bytes) -> void* {
    void* p = ws + off;
    off += (bytes + 255) & ~(size_t)255;
    return p;
  };
  unsigned short* WT = (unsigned short*)alloc(WT_BYTES);
  float* xrc  = (float*)alloc((size_t)CH * BT_ROWBYTES);
  unsigned short* xrL = (unsigned short*)alloc((size_t)CH * PL_BYTES);
  unsigned short* Qpl = (unsigned short*)alloc((size_t)CH * PL_BYTES);
  unsigned short* Kpl = (unsigned short*)alloc((size_t)CH * PL_BYTES);
  float* Vc   = (float*)alloc((size_t)CH * BT_ROWBYTES);
  float* attc = (float*)alloc((size_t)CH * BT_ROWBYTES);
  float* Sc   = (float*)alloc((size_t)CH * NN * NN * 4);
  float* lsec = (float*)alloc((size_t)CH * NN * 4);
  float* pmc  = (float*)alloc((size_t)CH * 4 * NN * 4);
  float* psc  = (float*)alloc((size_t)CH * 4 * NN * 4);
  unsigned long long* cpkc = (unsigned long long*)alloc((size_t)CH * NN * 8);

  k_prep_w<<<2, TPB, 0, stream>>>(Wq, Wk, WT);

  for (int c0 = 0; c0 < BTT; c0 += CH) {
    const size_t elemoff = (size_t)c0 * NN * DD;
    const float* xb  = x + elemoff;
    const float* ab  = adj + elemoff;
    float* outb = out + elemoff;
    int n4c = CH * NN * DD / 4;

    k_add<<<n4c / TPB, TPB, 0, stream>>>(xb, ab, xrc, xrL, n4c);

    k_gemm_qk_limb<<<CH * 4, TPB, 0, stream>>>(xrL, WT,           bq, Qpl);
    k_gemm_qk_limb<<<CH * 4, TPB, 0, stream>>>(xrL, WT + 3*16384, bk, Kpl);
    k_gemm_bias_f16<<<CH * 4, TPB, 0, stream>>>(xrc, Wv, bv, Vc);

    k_scores_mfma<<<CH * 16, TPB, 0, stream>>>(Qpl, Kpl, Sc, pmc, psc);
    k_lse_combine<<<CH * 2, TPB, 0, stream>>>(pmc, psc, lsec, CH * NN);
    (void)hipMemsetAsync(cpkc, 0, (size_t)CH * NN * 8, stream);
    k_pv_f16<<<CH * 8, TPB, 0, stream>>>(Sc, lsec, Vc, attc, cpkc);

    k_wo_ln_ffn<<<CH * 4, TPB, 0, stream>>>(attc, cpkc, Wo, bo, xrc,
                                            W1, b1, W2, b2, outb);
  }
}